// Round 5
// baseline (357.000 us; speedup 1.0000x reference)
//
#include <hip/hip_runtime.h>

// MoV3D: 3D local attention, window +-2 (125 offsets), B=2 C=32 H=W=D=48, 4 heads x 8 ch.
// Block = (b, head, 4x8x16 tile), 2 z-voxels/thread. K halo staged as fp16 channel-pairs:
// LDS word(sp,p) = {k[8p+h][sp], k[8p+4+h][sp]}, sp = lx*240+ly*20+lz over 8x12x20 halo,
// line (4 words = all 8 head channels at sp) XOR-swizzled: l = sp ^ ((sp>>3)&7).
// 30KB LDS -> 5 blocks/CU. Scores via v_dot2_f32_f16 (fp32 accum), log2 domain -> exp2.
// OOB taps: score forced to -16384 -> exp2==0 (== reference -1000 softmax underflow);
// staging therefore only needs IN-BOUNDS addresses (single flat clamp), not correct data.

#define S_PLANE 2304      // 48*48
#define S_CHAN 110592     // 48*48*48
#define TOTAL  7077888    // 2*32*S_CHAN
#define NH 4

typedef _Float16 h2 __attribute__((ext_vector_type(2)));

__device__ __forceinline__ float dot2(h2 a, h2 b, float c) {
#if __has_builtin(__builtin_amdgcn_fdot2)
    return __builtin_amdgcn_fdot2(a, b, c, false);
#else
    return fmaf((float)a[0], (float)b[0], fmaf((float)a[1], (float)b[1], c));
#endif
}

__device__ __forceinline__ h2 bc(unsigned w) { return __builtin_bit_cast(h2, w); }

__global__ __launch_bounds__(256, 5) void mov3d_kernel(
    const float* __restrict__ xq, const float* __restrict__ xk,
    float* __restrict__ out)
{
    __shared__ __align__(16) unsigned kw[7680];   // 30 KB

    const int tid = threadIdx.x;
    const int tz = tid & 7;           // 8 z-threads (2 voxels each)
    const int ty = (tid >> 3) & 7;    // 8
    const int tx = tid >> 6;          // 4

    int blk = blockIdx.x;             // 1728 = 4(h) * [2(b) * 12(xt) * 6(yt) * 3(zt)]
    const int h = blk / 432;
    int rem = blk - h * 432;
    const int zt = rem % 3;  rem /= 3;
    const int yt = rem % 6;  rem /= 6;
    const int xt = rem % 12;
    const int b  = rem / 12;

    const int x0 = xt * 4, y0 = yt * 8, z0 = zt * 16;
    const int x = x0 + tx, y = y0 + ty, zb = z0 + 2 * tz;
    const unsigned spA = (unsigned)(x * S_PLANE + y * 48 + zb);
    const int bbase = b * (32 * S_CHAN);

    // hd^-0.5 * log2(e): scores in log2 domain
    const float QSCALE = 0.35355339059327373f * 1.4426950408889634f;

    // ---- q load & fp16 pack: qA/qB[p] = {q[8p+h], q[8p+4+h]} for voxel A/B ----
    float2 qf[8];
#pragma unroll
    for (int k = 0; k < 8; ++k)
        qf[k] = *(const float2*)&xq[(unsigned)(bbase + (4 * k + h) * S_CHAN) + spA];
    h2 qA[4], qB[4];
#pragma unroll
    for (int p = 0; p < 4; ++p) {
        qA[p] = h2{(_Float16)(qf[2 * p].x * QSCALE), (_Float16)(qf[2 * p + 1].x * QSCALE)};
        qB[p] = h2{(_Float16)(qf[2 * p].y * QSCALE), (_Float16)(qf[2 * p + 1].y * QSCALE)};
    }

    // ---- stage K halo: 960 sp-pairs; thread handles sp = 2*(i*256+tid) ----
    const int sBase = bbase + h * S_CHAN;
#pragma unroll
    for (int i = 0; i < 4; ++i) {
        const int u = i * 256 + tid;
        if (u < 960) {
            const int sp = 2 * u;
            const int lx = sp / 240;
            const int r  = sp - lx * 240;
            const int ly = r / 20;
            const int lz = r - ly * 20;
            const int f = sBase + (x0 - 2 + lx) * S_PLANE + (y0 - 2 + ly) * 48 + (z0 - 2 + lz);
            uint4 W0, W1;
#pragma unroll
            for (int p = 0; p < 4; ++p) {
                const int aA = min(max(f + p * (8 * S_CHAN), 0), TOTAL - 2);
                const int aB = min(max(f + p * (8 * S_CHAN) + 4 * S_CHAN, 0), TOTAL - 2);
                const float2 vA = *(const float2*)&xk[aA];
                const float2 vB = *(const float2*)&xk[aB];
                const unsigned w0 = __builtin_bit_cast(unsigned, h2{(_Float16)vA.x, (_Float16)vB.x});
                const unsigned w1 = __builtin_bit_cast(unsigned, h2{(_Float16)vA.y, (_Float16)vB.y});
                ((unsigned*)&W0)[p] = w0;
                ((unsigned*)&W1)[p] = w1;
            }
            const int l0 = sp ^ ((sp >> 3) & 7);
            const int s1 = sp + 1;
            const int l1 = s1 ^ ((s1 >> 3) & 7);
            *(uint4*)&kw[l0 * 4] = W0;
            *(uint4*)&kw[l1 * 4] = W1;
        }
    }
    __syncthreads();   // single barrier

    // z-window validity: slot u covers gz = zb-2+u (voxel A taps u=0..4, B taps u=1..5)
    bool vu[6];
#pragma unroll
    for (int u = 0; u < 6; ++u) vu[u] = (unsigned)(zb - 2 + u) < 48u;

    float lA = 0.f, axA = 0.f, ayA = 0.f, azA = 0.f;
    float lB = 0.f, axB = 0.f, ayB = 0.f, azB = 0.f;
    const int spb = (tx + 2) * 240 + (ty + 2) * 20 + 2 * tz;
    const float NEG = -16384.f;   // exp2 -> exactly 0

    __builtin_amdgcn_s_setprio(1);
#pragma unroll
    for (int dx = -2; dx <= 2; ++dx) {
        const bool vx = (unsigned)(x + dx) < 48u;
        const float fdx = (float)dx;
#pragma unroll
        for (int dy = -2; dy <= 2; ++dy) {
            const bool vxy = vx && ((unsigned)(y + dy) < 48u);
            const float fdy = (float)dy;
            const int sp0 = spb + dx * 240 + dy * 20;

            float sA[5], sB[5];
#pragma unroll
            for (int u = 0; u < 6; ++u) {
                const int spu = sp0 + u;
                const int lu = spu ^ ((spu >> 3) & 7);
                const uint4 W = *(const uint4*)&kw[lu * 4];
                const h2 w0 = bc(W.x), w1 = bc(W.y), w2 = bc(W.z), w3 = bc(W.w);
                if (u < 5)
                    sA[u] = dot2(qA[0], w0, dot2(qA[1], w1, dot2(qA[2], w2, dot2(qA[3], w3, 0.f))));
                if (u > 0)
                    sB[u - 1] = dot2(qB[0], w0, dot2(qB[1], w1, dot2(qB[2], w2, dot2(qB[3], w3, 0.f))));
            }

            const float eA0 = exp2f((vxy && vu[0]) ? sA[0] : NEG);
            const float eA1 = exp2f((vxy && vu[1]) ? sA[1] : NEG);
            const float eA2 = exp2f((vxy && vu[2]) ? sA[2] : NEG);
            const float eA3 = exp2f((vxy && vu[3]) ? sA[3] : NEG);
            const float eA4 = exp2f((vxy && vu[4]) ? sA[4] : NEG);
            const float eB0 = exp2f((vxy && vu[1]) ? sB[0] : NEG);
            const float eB1 = exp2f((vxy && vu[2]) ? sB[1] : NEG);
            const float eB2 = exp2f((vxy && vu[3]) ? sB[2] : NEG);
            const float eB3 = exp2f((vxy && vu[4]) ? sB[3] : NEG);
            const float eB4 = exp2f((vxy && vu[5]) ? sB[4] : NEG);

            const float wsA = ((eA0 + eA1) + (eA2 + eA3)) + eA4;
            const float wsB = ((eB0 + eB1) + (eB2 + eB3)) + eB4;
            lA += wsA;  lB += wsB;
            axA = fmaf(fdx, wsA, axA);  axB = fmaf(fdx, wsB, axB);
            ayA = fmaf(fdy, wsA, ayA);  ayB = fmaf(fdy, wsB, ayB);
            azA += fmaf(2.f, eA4 - eA0, eA3 - eA1);
            azB += fmaf(2.f, eB4 - eB0, eB3 - eB1);
        }
    }
    __builtin_amdgcn_s_setprio(0);

    const float rA = 0.25f / lA;
    const float rB = 0.25f / lB;
    const unsigned ob = (unsigned)b * (3 * S_CHAN);
    atomicAdd(&out[ob + 0u * S_CHAN + spA],     axA * rA);
    atomicAdd(&out[ob + 0u * S_CHAN + spA + 1], axB * rB);
    atomicAdd(&out[ob + 1u * S_CHAN + spA],     ayA * rA);
    atomicAdd(&out[ob + 1u * S_CHAN + spA + 1], ayB * rB);
    atomicAdd(&out[ob + 2u * S_CHAN + spA],     azA * rA);
    atomicAdd(&out[ob + 2u * S_CHAN + spA + 1], azB * rB);
}

extern "C" void kernel_launch(void* const* d_in, const int* in_sizes, int n_in,
                              void* d_out, int out_size, void* d_ws, size_t ws_size,
                              hipStream_t stream) {
    const float* xq = (const float*)d_in[0];
    const float* xk = (const float*)d_in[1];
    float* out = (float*)d_out;
    // zero output (heads accumulate via atomicAdd); memset node is graph-capturable
    hipMemsetAsync(out, 0, (size_t)out_size * sizeof(float), stream);
    // grid: 4(head) * 2(b) * 12(xt) * 6(yt) * 3(zt) = 1728 blocks of 256 threads
    mov3d_kernel<<<1728, 256, 0, stream>>>(xq, xk, out);
}

// Round 6
// 281.452 us; speedup vs baseline: 1.2684x; 1.2684x over previous
//
#include <hip/hip_runtime.h>

// MoV3D: 3D local attention, window +-2 (125 offsets), B=2 C=32 H=W=D=48, 4 heads x 8 ch.
// Block = (b, head, 4x8x16 tile), 2 z-voxels/thread. K halo staged as fp16 channel-pairs:
// LDS word(sp,p) = {k[8p+h][sp], k[8p+4+h][sp]}, sp = lx*240+ly*20+lz over 8x12x20 halo,
// line (4 words = all 8 head channels at sp) XOR-swizzled: l = sp ^ ((sp>>3)&7).
// 30KB LDS, launch_bounds(256,4) -> 4 blocks/CU (16 waves). Scores via v_dot2_f32_f16
// (fp32 accum), log2 domain -> 1-instr exp2. OOB taps: score -> -16384 -> exp2==0
// (== reference -1000 softmax underflow); staged addresses only need to be IN-BOUNDS
// (single flat clamp), masked taps never contribute.
// NOTE: staging uses ONLY named scalar temporaries (no pointer-cast element writes) --
// round-5's address-taken uint4 alloca spilled to scratch (537 MB HBM writes).

#define S_PLANE 2304      // 48*48
#define S_CHAN 110592     // 48*48*48
#define TOTAL  7077888    // 2*32*S_CHAN

typedef _Float16 h2 __attribute__((ext_vector_type(2)));

__device__ __forceinline__ float dot2(h2 a, h2 b, float c) {
#if __has_builtin(__builtin_amdgcn_fdot2)
    return __builtin_amdgcn_fdot2(a, b, c, false);
#else
    return fmaf((float)a[0], (float)b[0], fmaf((float)a[1], (float)b[1], c));
#endif
}

__device__ __forceinline__ h2 bc(unsigned w) { return __builtin_bit_cast(h2, w); }
__device__ __forceinline__ unsigned pk(float a, float b) {
    return __builtin_bit_cast(unsigned, h2{(_Float16)a, (_Float16)b});
}

__global__ __launch_bounds__(256, 4) void mov3d_kernel(
    const float* __restrict__ xq, const float* __restrict__ xk,
    float* __restrict__ out)
{
    __shared__ __align__(16) unsigned kw[7680];   // 30 KB

    const int tid = threadIdx.x;
    const int tz = tid & 7;           // 8 z-threads (2 voxels each)
    const int ty = (tid >> 3) & 7;    // 8
    const int tx = tid >> 6;          // 4

    int blk = blockIdx.x;             // 1728 = 4(h) * [2(b) * 12(xt) * 6(yt) * 3(zt)]
    const int h = blk / 432;
    int rem = blk - h * 432;
    const int zt = rem % 3;  rem /= 3;
    const int yt = rem % 6;  rem /= 6;
    const int xt = rem % 12;
    const int b  = rem / 12;

    const int x0 = xt * 4, y0 = yt * 8, z0 = zt * 16;
    const int x = x0 + tx, y = y0 + ty, zb = z0 + 2 * tz;
    const unsigned spA = (unsigned)(x * S_PLANE + y * 48 + zb);
    const int bbase = b * (32 * S_CHAN);

    // hd^-0.5 * log2(e): scores in log2 domain
    const float QSCALE = 0.35355339059327373f * 1.4426950408889634f;

    // ---- q load & fp16 pack: qA/qB[p] = {q[8p+h], q[8p+4+h]} for voxel A/B ----
    const float2 qf0 = *(const float2*)&xq[(unsigned)(bbase + (h     ) * S_CHAN) + spA];
    const float2 qf1 = *(const float2*)&xq[(unsigned)(bbase + (h +  4) * S_CHAN) + spA];
    const float2 qf2 = *(const float2*)&xq[(unsigned)(bbase + (h +  8) * S_CHAN) + spA];
    const float2 qf3 = *(const float2*)&xq[(unsigned)(bbase + (h + 12) * S_CHAN) + spA];
    const float2 qf4 = *(const float2*)&xq[(unsigned)(bbase + (h + 16) * S_CHAN) + spA];
    const float2 qf5 = *(const float2*)&xq[(unsigned)(bbase + (h + 20) * S_CHAN) + spA];
    const float2 qf6 = *(const float2*)&xq[(unsigned)(bbase + (h + 24) * S_CHAN) + spA];
    const float2 qf7 = *(const float2*)&xq[(unsigned)(bbase + (h + 28) * S_CHAN) + spA];
    h2 qA[4], qB[4];
    qA[0] = h2{(_Float16)(qf0.x * QSCALE), (_Float16)(qf1.x * QSCALE)};
    qA[1] = h2{(_Float16)(qf2.x * QSCALE), (_Float16)(qf3.x * QSCALE)};
    qA[2] = h2{(_Float16)(qf4.x * QSCALE), (_Float16)(qf5.x * QSCALE)};
    qA[3] = h2{(_Float16)(qf6.x * QSCALE), (_Float16)(qf7.x * QSCALE)};
    qB[0] = h2{(_Float16)(qf0.y * QSCALE), (_Float16)(qf1.y * QSCALE)};
    qB[1] = h2{(_Float16)(qf2.y * QSCALE), (_Float16)(qf3.y * QSCALE)};
    qB[2] = h2{(_Float16)(qf4.y * QSCALE), (_Float16)(qf5.y * QSCALE)};
    qB[3] = h2{(_Float16)(qf6.y * QSCALE), (_Float16)(qf7.y * QSCALE)};

    // ---- stage K halo: 960 sp-pairs; thread u handles sp = 2u, 2u+1 ----
    const int sBase = bbase + h * S_CHAN;
#pragma unroll
    for (int i = 0; i < 4; ++i) {
        const int u = i * 256 + tid;
        if (u < 960) {
            const int sp = 2 * u;
            const int lx = sp / 240;
            const int r  = sp - lx * 240;
            const int ly = r / 20;
            const int lz = r - ly * 20;
            const int f = sBase + (x0 - 2 + lx) * S_PLANE + (y0 - 2 + ly) * 48 + (z0 - 2 + lz);
            const int a0 = min(max(f,                0), TOTAL - 2);
            const int a1 = min(max(f +  8 * S_CHAN,  0), TOTAL - 2);
            const int a2 = min(max(f + 16 * S_CHAN,  0), TOTAL - 2);
            const int a3 = min(max(f + 24 * S_CHAN,  0), TOTAL - 2);
            const int c0 = min(max(f +  4 * S_CHAN,  0), TOTAL - 2);
            const int c1 = min(max(f + 12 * S_CHAN,  0), TOTAL - 2);
            const int c2 = min(max(f + 20 * S_CHAN,  0), TOTAL - 2);
            const int c3 = min(max(f + 28 * S_CHAN,  0), TOTAL - 2);
            const float2 vA0 = *(const float2*)&xk[a0];
            const float2 vA1 = *(const float2*)&xk[a1];
            const float2 vA2 = *(const float2*)&xk[a2];
            const float2 vA3 = *(const float2*)&xk[a3];
            const float2 vB0 = *(const float2*)&xk[c0];
            const float2 vB1 = *(const float2*)&xk[c1];
            const float2 vB2 = *(const float2*)&xk[c2];
            const float2 vB3 = *(const float2*)&xk[c3];
            const unsigned p00 = pk(vA0.x, vB0.x), p01 = pk(vA1.x, vB1.x);
            const unsigned p02 = pk(vA2.x, vB2.x), p03 = pk(vA3.x, vB3.x);
            const unsigned p10 = pk(vA0.y, vB0.y), p11 = pk(vA1.y, vB1.y);
            const unsigned p12 = pk(vA2.y, vB2.y), p13 = pk(vA3.y, vB3.y);
            const uint4 W0 = {p00, p01, p02, p03};
            const uint4 W1 = {p10, p11, p12, p13};
            const int l0 = sp ^ ((sp >> 3) & 7);
            const int s1 = sp + 1;
            const int l1 = s1 ^ ((s1 >> 3) & 7);
            *(uint4*)&kw[l0 * 4] = W0;
            *(uint4*)&kw[l1 * 4] = W1;
        }
    }
    __syncthreads();   // single barrier

    // z-window validity: slot u covers gz = zb-2+u (voxel A taps u=0..4, B taps u=1..5)
    bool vu[6];
#pragma unroll
    for (int u = 0; u < 6; ++u) vu[u] = (unsigned)(zb - 2 + u) < 48u;

    float lA = 0.f, axA = 0.f, ayA = 0.f, azA = 0.f;
    float lB = 0.f, axB = 0.f, ayB = 0.f, azB = 0.f;
    const int spb = (tx + 2) * 240 + (ty + 2) * 20 + 2 * tz;
    const float NEG = -16384.f;   // exp2 -> exactly 0

    __builtin_amdgcn_s_setprio(1);
#pragma unroll
    for (int dx = -2; dx <= 2; ++dx) {
        const bool vx = (unsigned)(x + dx) < 48u;
        const float fdx = (float)dx;
#pragma unroll
        for (int dy = -2; dy <= 2; ++dy) {
            const bool vxy = vx && ((unsigned)(y + dy) < 48u);
            const float fdy = (float)dy;
            const int sp0 = spb + dx * 240 + dy * 20;

            float sA[5], sB[5];
#pragma unroll
            for (int u = 0; u < 6; ++u) {
                const int spu = sp0 + u;
                const int lu = spu ^ ((spu >> 3) & 7);
                const uint4 W = *(const uint4*)&kw[lu * 4];
                const h2 w0 = bc(W.x), w1 = bc(W.y), w2 = bc(W.z), w3 = bc(W.w);
                if (u < 5)
                    sA[u] = dot2(qA[0], w0, dot2(qA[1], w1, dot2(qA[2], w2, dot2(qA[3], w3, 0.f))));
                if (u > 0)
                    sB[u - 1] = dot2(qB[0], w0, dot2(qB[1], w1, dot2(qB[2], w2, dot2(qB[3], w3, 0.f))));
            }

            const float eA0 = exp2f((vxy && vu[0]) ? sA[0] : NEG);
            const float eA1 = exp2f((vxy && vu[1]) ? sA[1] : NEG);
            const float eA2 = exp2f((vxy && vu[2]) ? sA[2] : NEG);
            const float eA3 = exp2f((vxy && vu[3]) ? sA[3] : NEG);
            const float eA4 = exp2f((vxy && vu[4]) ? sA[4] : NEG);
            const float eB0 = exp2f((vxy && vu[1]) ? sB[0] : NEG);
            const float eB1 = exp2f((vxy && vu[2]) ? sB[1] : NEG);
            const float eB2 = exp2f((vxy && vu[3]) ? sB[2] : NEG);
            const float eB3 = exp2f((vxy && vu[4]) ? sB[3] : NEG);
            const float eB4 = exp2f((vxy && vu[5]) ? sB[4] : NEG);

            const float wsA = ((eA0 + eA1) + (eA2 + eA3)) + eA4;
            const float wsB = ((eB0 + eB1) + (eB2 + eB3)) + eB4;
            lA += wsA;  lB += wsB;
            axA = fmaf(fdx, wsA, axA);  axB = fmaf(fdx, wsB, axB);
            ayA = fmaf(fdy, wsA, ayA);  ayB = fmaf(fdy, wsB, ayB);
            azA += fmaf(2.f, eA4 - eA0, eA3 - eA1);
            azB += fmaf(2.f, eB4 - eB0, eB3 - eB1);
        }
    }
    __builtin_amdgcn_s_setprio(0);

    const float rA = 0.25f / lA;
    const float rB = 0.25f / lB;
    const unsigned ob = (unsigned)b * (3 * S_CHAN);
    atomicAdd(&out[ob + 0u * S_CHAN + spA],     axA * rA);
    atomicAdd(&out[ob + 0u * S_CHAN + spA + 1], axB * rB);
    atomicAdd(&out[ob + 1u * S_CHAN + spA],     ayA * rA);
    atomicAdd(&out[ob + 1u * S_CHAN + spA + 1], ayB * rB);
    atomicAdd(&out[ob + 2u * S_CHAN + spA],     azA * rA);
    atomicAdd(&out[ob + 2u * S_CHAN + spA + 1], azB * rB);
}

extern "C" void kernel_launch(void* const* d_in, const int* in_sizes, int n_in,
                              void* d_out, int out_size, void* d_ws, size_t ws_size,
                              hipStream_t stream) {
    const float* xq = (const float*)d_in[0];
    const float* xk = (const float*)d_in[1];
    float* out = (float*)d_out;
    // zero output (heads accumulate via atomicAdd); memset node is graph-capturable
    hipMemsetAsync(out, 0, (size_t)out_size * sizeof(float), stream);
    // grid: 4(head) * 2(b) * 12(xt) * 6(yt) * 3(zt) = 1728 blocks of 256 threads
    mov3d_kernel<<<1728, 256, 0, stream>>>(xq, xk, out);
}

// Round 7
// 74.436 us; speedup vs baseline: 4.7960x; 3.7811x over previous
//
#include <hip/hip_runtime.h>

// MoV3D: 3D local attention, window +-2 (125 offsets), B=2 C=32 H=W=D=48, 4 heads x 8 ch.
// Block = (b, head, 4x8x16 tile), 2 z-voxels/thread. K halo staged as fp16 channel-pairs:
// LDS line(sp) = 4 words {k[h],k[h+4]},{k[h+8],k[h+12]},{k[h+16],k[h+20]},{k[h+24],k[h+28]}
// at spatial sp = lx*240+ly*20+lz (8x12x20 halo). Line index PARITY-SPLIT swizzled:
// l = (sp>>1) + (sp&1)*960  -> bank-group g = bits[3:1] of sp -> the 8 lanes of each b128
// phase (fixed ty, tz=0..7, sp=C'+2tz) hit 8 DISTINCT bank groups: conflict-free.
// 30KB LDS, launch_bounds(256,4). Scores via v_dot2_f32_f16 (fp32 accum), log2 domain ->
// 1-instr exp2. OOB taps: score -> -16384 -> exp2==0 (== reference -1000 underflow);
// staged addresses only need to be IN-BOUNDS (flat clamp), masked taps never contribute.
// RULE-#20 DISCIPLINE: no local arrays anywhere in the kernel -- every per-thread value
// is a named scalar (rounds 5/6 lost 3x to alloca/scratch traffic from unrolled arrays).

#define S_PLANE 2304      // 48*48
#define S_CHAN 110592     // 48*48*48
#define TOTAL  7077888    // 2*32*S_CHAN

typedef _Float16 h2 __attribute__((ext_vector_type(2)));

__device__ __forceinline__ float dot2(h2 a, h2 b, float c) {
#if __has_builtin(__builtin_amdgcn_fdot2)
    return __builtin_amdgcn_fdot2(a, b, c, false);
#else
    return fmaf((float)a[0], (float)b[0], fmaf((float)a[1], (float)b[1], c));
#endif
}

__device__ __forceinline__ h2 bc(unsigned w) { return __builtin_bit_cast(h2, w); }
__device__ __forceinline__ unsigned pk(float a, float b) {
    return __builtin_bit_cast(unsigned, h2{(_Float16)a, (_Float16)b});
}

__global__ __launch_bounds__(256, 4) void mov3d_kernel(
    const float* __restrict__ xq, const float* __restrict__ xk,
    float* __restrict__ out)
{
    __shared__ __align__(16) unsigned kw[7680];   // 1920 lines * 16 B = 30 KB

    const int tid = threadIdx.x;
    const int tz = tid & 7;           // 8 z-threads (2 voxels each)
    const int ty = (tid >> 3) & 7;    // 8
    const int tx = tid >> 6;          // 4

    int blk = blockIdx.x;             // 1728 = 4(h) * [2(b) * 12(xt) * 6(yt) * 3(zt)]
    const int h = blk / 432;
    int rem = blk - h * 432;
    const int zt = rem % 3;  rem /= 3;
    const int yt = rem % 6;  rem /= 6;
    const int xt = rem % 12;
    const int b  = rem / 12;

    const int x0 = xt * 4, y0 = yt * 8, z0 = zt * 16;
    const int x = x0 + tx, y = y0 + ty, zb = z0 + 2 * tz;
    const unsigned spA = (unsigned)(x * S_PLANE + y * 48 + zb);
    const int bbase = b * (32 * S_CHAN);

    // hd^-0.5 * log2(e): scores in log2 domain
    const float QSCALE = 0.35355339059327373f * 1.4426950408889634f;

    // ---- q load & fp16 pack: qA*/qB* = {q[8p+h], q[8p+4+h]} for voxel A/B ----
    const float2 qf0 = *(const float2*)&xq[(unsigned)(bbase + (h     ) * S_CHAN) + spA];
    const float2 qf1 = *(const float2*)&xq[(unsigned)(bbase + (h +  4) * S_CHAN) + spA];
    const float2 qf2 = *(const float2*)&xq[(unsigned)(bbase + (h +  8) * S_CHAN) + spA];
    const float2 qf3 = *(const float2*)&xq[(unsigned)(bbase + (h + 12) * S_CHAN) + spA];
    const float2 qf4 = *(const float2*)&xq[(unsigned)(bbase + (h + 16) * S_CHAN) + spA];
    const float2 qf5 = *(const float2*)&xq[(unsigned)(bbase + (h + 20) * S_CHAN) + spA];
    const float2 qf6 = *(const float2*)&xq[(unsigned)(bbase + (h + 24) * S_CHAN) + spA];
    const float2 qf7 = *(const float2*)&xq[(unsigned)(bbase + (h + 28) * S_CHAN) + spA];
    const h2 qA0 = h2{(_Float16)(qf0.x * QSCALE), (_Float16)(qf1.x * QSCALE)};
    const h2 qA1 = h2{(_Float16)(qf2.x * QSCALE), (_Float16)(qf3.x * QSCALE)};
    const h2 qA2 = h2{(_Float16)(qf4.x * QSCALE), (_Float16)(qf5.x * QSCALE)};
    const h2 qA3 = h2{(_Float16)(qf6.x * QSCALE), (_Float16)(qf7.x * QSCALE)};
    const h2 qB0 = h2{(_Float16)(qf0.y * QSCALE), (_Float16)(qf1.y * QSCALE)};
    const h2 qB1 = h2{(_Float16)(qf2.y * QSCALE), (_Float16)(qf3.y * QSCALE)};
    const h2 qB2 = h2{(_Float16)(qf4.y * QSCALE), (_Float16)(qf5.y * QSCALE)};
    const h2 qB3 = h2{(_Float16)(qf6.y * QSCALE), (_Float16)(qf7.y * QSCALE)};

    // ---- stage K halo: thread u covers sp = 2u (line u) and 2u+1 (line u+960) ----
    const int sBase = bbase + h * S_CHAN;
#pragma unroll
    for (int i = 0; i < 4; ++i) {
        const int u = i * 256 + tid;
        if (u < 960) {
            const int sp = 2 * u;
            const int lx = sp / 240;
            const int r  = sp - lx * 240;
            const int ly = r / 20;
            const int lz = r - ly * 20;
            const int f = sBase + (x0 - 2 + lx) * S_PLANE + (y0 - 2 + ly) * 48 + (z0 - 2 + lz);
            const int a0 = min(max(f,                0), TOTAL - 2);
            const int a1 = min(max(f +  8 * S_CHAN,  0), TOTAL - 2);
            const int a2 = min(max(f + 16 * S_CHAN,  0), TOTAL - 2);
            const int a3 = min(max(f + 24 * S_CHAN,  0), TOTAL - 2);
            const int c0 = min(max(f +  4 * S_CHAN,  0), TOTAL - 2);
            const int c1 = min(max(f + 12 * S_CHAN,  0), TOTAL - 2);
            const int c2 = min(max(f + 20 * S_CHAN,  0), TOTAL - 2);
            const int c3 = min(max(f + 28 * S_CHAN,  0), TOTAL - 2);
            const float2 vA0 = *(const float2*)&xk[a0];
            const float2 vA1 = *(const float2*)&xk[a1];
            const float2 vA2 = *(const float2*)&xk[a2];
            const float2 vA3 = *(const float2*)&xk[a3];
            const float2 vB0 = *(const float2*)&xk[c0];
            const float2 vB1 = *(const float2*)&xk[c1];
            const float2 vB2 = *(const float2*)&xk[c2];
            const float2 vB3 = *(const float2*)&xk[c3];
            const uint4 W0 = {pk(vA0.x, vB0.x), pk(vA1.x, vB1.x),
                              pk(vA2.x, vB2.x), pk(vA3.x, vB3.x)};
            const uint4 W1 = {pk(vA0.y, vB0.y), pk(vA1.y, vB1.y),
                              pk(vA2.y, vB2.y), pk(vA3.y, vB3.y)};
            *(uint4*)&kw[u * 4] = W0;               // sp even -> line u
            *(uint4*)&kw[(u + 960) * 4] = W1;       // sp odd  -> line u+960
        }
    }
    __syncthreads();   // single barrier

    // z-window validity (named scalars): slot U covers abs z = zb-2+U
    const bool vz0 = (unsigned)(zb - 2) < 48u;
    const bool vz1 = (unsigned)(zb - 1) < 48u;
    const bool vz2 = true;                       // zb in [0,48)
    const bool vz3 = (unsigned)(zb + 1) < 48u;
    const bool vz4 = (unsigned)(zb + 2) < 48u;
    const bool vz5 = (unsigned)(zb + 3) < 48u;

    float lA = 0.f, axA = 0.f, ayA = 0.f, azA = 0.f;
    float lB = 0.f, axB = 0.f, ayB = 0.f, azB = 0.f;
    const int spb = (tx + 2) * 240 + (ty + 2) * 20 + 2 * tz;
    const float NEG = -16384.f;   // exp2 -> exactly 0

    // one tap: window slot U; voxel A tap index U (dz=U-2), voxel B tap U-1 (dz=U-3)
#define DO_TAP(U, VZ) do {                                                    \
        const int spu = sp0 + (U);                                            \
        const int lu = (spu >> 1) + (spu & 1) * 960;                          \
        const uint4 W = *(const uint4*)&kw[lu * 4];                           \
        const h2 w0 = bc(W.x), w1 = bc(W.y), w2 = bc(W.z), w3 = bc(W.w);      \
        if ((U) < 5) {                                                        \
            const float s = dot2(qA0, w0, dot2(qA1, w1,                       \
                              dot2(qA2, w2, dot2(qA3, w3, 0.f))));            \
            const float e = exp2f((vxy && (VZ)) ? s : NEG);                   \
            wsA += e;                                                         \
            azA = fmaf((float)((U) - 2), e, azA);                             \
        }                                                                     \
        if ((U) > 0) {                                                        \
            const float s = dot2(qB0, w0, dot2(qB1, w1,                       \
                              dot2(qB2, w2, dot2(qB3, w3, 0.f))));            \
            const float e = exp2f((vxy && (VZ)) ? s : NEG);                   \
            wsB += e;                                                         \
            azB = fmaf((float)((U) - 3), e, azB);                             \
        }                                                                     \
    } while (0)

    __builtin_amdgcn_s_setprio(1);
#pragma unroll
    for (int dx = -2; dx <= 2; ++dx) {
        const bool vx = (unsigned)(x + dx) < 48u;
        const float fdx = (float)dx;
#pragma unroll
        for (int dy = -2; dy <= 2; ++dy) {
            const bool vxy = vx && ((unsigned)(y + dy) < 48u);
            const float fdy = (float)dy;
            const int sp0 = spb + dx * 240 + dy * 20;

            float wsA = 0.f, wsB = 0.f;
            DO_TAP(0, vz0);
            DO_TAP(1, vz1);
            DO_TAP(2, vz2);
            DO_TAP(3, vz3);
            DO_TAP(4, vz4);
            DO_TAP(5, vz5);

            lA += wsA;  lB += wsB;
            axA = fmaf(fdx, wsA, axA);  axB = fmaf(fdx, wsB, axB);
            ayA = fmaf(fdy, wsA, ayA);  ayB = fmaf(fdy, wsB, ayB);
        }
    }
    __builtin_amdgcn_s_setprio(0);
#undef DO_TAP

    const float rA = 0.25f / lA;
    const float rB = 0.25f / lB;
    const unsigned ob = (unsigned)b * (3 * S_CHAN);
    atomicAdd(&out[ob + 0u * S_CHAN + spA],     axA * rA);
    atomicAdd(&out[ob + 0u * S_CHAN + spA + 1], axB * rB);
    atomicAdd(&out[ob + 1u * S_CHAN + spA],     ayA * rA);
    atomicAdd(&out[ob + 1u * S_CHAN + spA + 1], ayB * rB);
    atomicAdd(&out[ob + 2u * S_CHAN + spA],     azA * rA);
    atomicAdd(&out[ob + 2u * S_CHAN + spA + 1], azB * rB);
}

extern "C" void kernel_launch(void* const* d_in, const int* in_sizes, int n_in,
                              void* d_out, int out_size, void* d_ws, size_t ws_size,
                              hipStream_t stream) {
    const float* xq = (const float*)d_in[0];
    const float* xk = (const float*)d_in[1];
    float* out = (float*)d_out;
    // zero output (heads accumulate via atomicAdd); memset node is graph-capturable
    hipMemsetAsync(out, 0, (size_t)out_size * sizeof(float), stream);
    // grid: 4(head) * 2(b) * 12(xt) * 6(yt) * 3(zt) = 1728 blocks of 256 threads
    mov3d_kernel<<<1728, 256, 0, stream>>>(xq, xk, out);
}

// Round 8
// 73.224 us; speedup vs baseline: 4.8754x; 1.0166x over previous
//
#include <hip/hip_runtime.h>

// MoV3D: 3D local attention, window +-2 (125 offsets), B=2 C=32 H=W=D=48, 4 heads x 8 ch.
// Block = (b, head, 4x8x16 tile), 2 z-voxels/thread. K halo staged as fp16 channel-pairs.
// LDS line (16B) = all 8 head channels at one spatial halo point (lx,ly,lz):
//   line = lx*120 + lz2*12 + ly  (+960 for odd lz), lz2 = lz>>1.
// ly coefficient = 1 --> stride-8 lane phases (measured: LDS processes b128 with ty
// varying within a phase; round-7 counter showed exactly 2-way on every phase with a
// ly-coeff-2 layout) hit 8 distinct bank groups: conflict-free reads.
// 30KB LDS, launch_bounds(256,5) -> 5 blocks/CU. Scores via v_dot2_f32_f16 (fp32 accum),
// log2 domain -> 1-instr exp2. OOB taps: score -> -16384 -> exp2==0 (== reference
// -1000 underflow); staged addresses only need IN-BOUNDS (flat clamp).
// RULE-#20: no local arrays; every per-thread value is a named scalar.

#define S_PLANE 2304      // 48*48
#define S_CHAN 110592     // 48*48*48
#define TOTAL  7077888    // 2*32*S_CHAN

typedef _Float16 h2 __attribute__((ext_vector_type(2)));

__device__ __forceinline__ float dot2(h2 a, h2 b, float c) {
#if __has_builtin(__builtin_amdgcn_fdot2)
    return __builtin_amdgcn_fdot2(a, b, c, false);
#else
    return fmaf((float)a[0], (float)b[0], fmaf((float)a[1], (float)b[1], c));
#endif
}

__device__ __forceinline__ h2 bc(unsigned w) { return __builtin_bit_cast(h2, w); }
__device__ __forceinline__ unsigned pk(float a, float b) {
    return __builtin_bit_cast(unsigned, h2{(_Float16)a, (_Float16)b});
}

__global__ __launch_bounds__(256, 5) void mov3d_kernel(
    const float* __restrict__ xq, const float* __restrict__ xk,
    float* __restrict__ out)
{
    __shared__ __align__(16) unsigned kw[7680];   // 1920 lines * 16 B = 30 KB

    const int tid = threadIdx.x;
    const int tz = tid & 7;           // 8 z-threads (2 voxels each)
    const int ty = (tid >> 3) & 7;    // 8
    const int tx = tid >> 6;          // 4 (wave index)

    int blk = blockIdx.x;             // 1728 = 4(h) * [2(b) * 12(xt) * 6(yt) * 3(zt)]
    const int h = blk / 432;
    int rem = blk - h * 432;
    const int zt = rem % 3;  rem /= 3;
    const int yt = rem % 6;  rem /= 6;
    const int xt = rem % 12;
    const int b  = rem / 12;

    const int x0 = xt * 4, y0 = yt * 8, z0 = zt * 16;
    const int x = x0 + tx, y = y0 + ty, zb = z0 + 2 * tz;
    const unsigned spA = (unsigned)(x * S_PLANE + y * 48 + zb);
    const int bbase = b * (32 * S_CHAN);

    // hd^-0.5 * log2(e): scores in log2 domain
    const float QSCALE = 0.35355339059327373f * 1.4426950408889634f;

    // ---- q load & fp16 pack: qA*/qB* = {q[8p+h], q[8p+4+h]} for voxel A/B ----
    const float2 qf0 = *(const float2*)&xq[(unsigned)(bbase + (h     ) * S_CHAN) + spA];
    const float2 qf1 = *(const float2*)&xq[(unsigned)(bbase + (h +  4) * S_CHAN) + spA];
    const float2 qf2 = *(const float2*)&xq[(unsigned)(bbase + (h +  8) * S_CHAN) + spA];
    const float2 qf3 = *(const float2*)&xq[(unsigned)(bbase + (h + 12) * S_CHAN) + spA];
    const float2 qf4 = *(const float2*)&xq[(unsigned)(bbase + (h + 16) * S_CHAN) + spA];
    const float2 qf5 = *(const float2*)&xq[(unsigned)(bbase + (h + 20) * S_CHAN) + spA];
    const float2 qf6 = *(const float2*)&xq[(unsigned)(bbase + (h + 24) * S_CHAN) + spA];
    const float2 qf7 = *(const float2*)&xq[(unsigned)(bbase + (h + 28) * S_CHAN) + spA];
    const h2 qA0 = h2{(_Float16)(qf0.x * QSCALE), (_Float16)(qf1.x * QSCALE)};
    const h2 qA1 = h2{(_Float16)(qf2.x * QSCALE), (_Float16)(qf3.x * QSCALE)};
    const h2 qA2 = h2{(_Float16)(qf4.x * QSCALE), (_Float16)(qf5.x * QSCALE)};
    const h2 qA3 = h2{(_Float16)(qf6.x * QSCALE), (_Float16)(qf7.x * QSCALE)};
    const h2 qB0 = h2{(_Float16)(qf0.y * QSCALE), (_Float16)(qf1.y * QSCALE)};
    const h2 qB1 = h2{(_Float16)(qf2.y * QSCALE), (_Float16)(qf3.y * QSCALE)};
    const h2 qB2 = h2{(_Float16)(qf4.y * QSCALE), (_Float16)(qf5.y * QSCALE)};
    const h2 qB3 = h2{(_Float16)(qf6.y * QSCALE), (_Float16)(qf7.y * QSCALE)};

    // ---- stage K halo: thread u covers lz pair (2*lz2, 2*lz2+1) at (lx,ly) ----
    // u in [0,960): lx = u/120, r = u%120, ly = r/10, lz2 = r%10 (global loads stay
    // z-consecutive via float2; line index uses the ly-coeff-1 packing).
    const int sBase = bbase + h * S_CHAN;
#pragma unroll
    for (int i = 0; i < 4; ++i) {
        const int u = i * 256 + tid;
        if (u < 960) {
            const int lx  = u / 120;
            const int r   = u - lx * 120;
            const int ly  = r / 10;
            const int lz2 = r - ly * 10;
            const int m = lx * 120 + lz2 * 12 + ly;   // even-parity line
            const int f = sBase + (x0 - 2 + lx) * S_PLANE + (y0 - 2 + ly) * 48
                        + (z0 - 2 + 2 * lz2);
            const int a0 = min(max(f,                0), TOTAL - 2);
            const int a1 = min(max(f +  8 * S_CHAN,  0), TOTAL - 2);
            const int a2 = min(max(f + 16 * S_CHAN,  0), TOTAL - 2);
            const int a3 = min(max(f + 24 * S_CHAN,  0), TOTAL - 2);
            const int c0 = min(max(f +  4 * S_CHAN,  0), TOTAL - 2);
            const int c1 = min(max(f + 12 * S_CHAN,  0), TOTAL - 2);
            const int c2 = min(max(f + 20 * S_CHAN,  0), TOTAL - 2);
            const int c3 = min(max(f + 28 * S_CHAN,  0), TOTAL - 2);
            const float2 vA0 = *(const float2*)&xk[a0];
            const float2 vA1 = *(const float2*)&xk[a1];
            const float2 vA2 = *(const float2*)&xk[a2];
            const float2 vA3 = *(const float2*)&xk[a3];
            const float2 vB0 = *(const float2*)&xk[c0];
            const float2 vB1 = *(const float2*)&xk[c1];
            const float2 vB2 = *(const float2*)&xk[c2];
            const float2 vB3 = *(const float2*)&xk[c3];
            const uint4 W0 = {pk(vA0.x, vB0.x), pk(vA1.x, vB1.x),
                              pk(vA2.x, vB2.x), pk(vA3.x, vB3.x)};
            const uint4 W1 = {pk(vA0.y, vB0.y), pk(vA1.y, vB1.y),
                              pk(vA2.y, vB2.y), pk(vA3.y, vB3.y)};
            *(uint4*)&kw[m * 4] = W0;               // lz even
            *(uint4*)&kw[(m + 960) * 4] = W1;       // lz odd
        }
    }
    __syncthreads();   // single barrier

    // z-window validity (named scalars): slot U covers abs z = zb-2+U
    const bool vz0 = (unsigned)(zb - 2) < 48u;
    const bool vz1 = (unsigned)(zb - 1) < 48u;
    const bool vz2 = true;                       // zb in [0,48)
    const bool vz3 = (unsigned)(zb + 1) < 48u;
    const bool vz4 = (unsigned)(zb + 2) < 48u;
    const bool vz5 = (unsigned)(zb + 3) < 48u;

    float lA = 0.f, axA = 0.f, ayA = 0.f, azA = 0.f;
    float lB = 0.f, axB = 0.f, ayB = 0.f, azB = 0.f;
    const float NEG = -16384.f;   // exp2 -> exactly 0

    // tap U: lz = 2tz+U -> lz2 = tz + (U>>1), parity = U&1
    // line = base + (U>>1)*12 + (U&1)*960 -> word offsets (U>>1)*48 + (U&1)*3840
#define DO_TAP(U, VZ) do {                                                    \
        const uint4 W = *(const uint4*)(pb + ((U) >> 1) * 48 + ((U) & 1) * 3840); \
        const h2 w0 = bc(W.x), w1 = bc(W.y), w2 = bc(W.z), w3 = bc(W.w);      \
        if ((U) < 5) {                                                        \
            const float s = dot2(qA0, w0, dot2(qA1, w1,                       \
                              dot2(qA2, w2, dot2(qA3, w3, 0.f))));            \
            const float e = exp2f((vxy && (VZ)) ? s : NEG);                   \
            wsA += e;                                                         \
            azA = fmaf((float)((U) - 2), e, azA);                             \
        }                                                                     \
        if ((U) > 0) {                                                        \
            const float s = dot2(qB0, w0, dot2(qB1, w1,                       \
                              dot2(qB2, w2, dot2(qB3, w3, 0.f))));            \
            const float e = exp2f((vxy && (VZ)) ? s : NEG);                   \
            wsB += e;                                                         \
            azB = fmaf((float)((U) - 3), e, azB);                             \
        }                                                                     \
    } while (0)

    __builtin_amdgcn_s_setprio(1);
#pragma unroll
    for (int dx = -2; dx <= 2; ++dx) {
        const bool vx = (unsigned)(x + dx) < 48u;
        const float fdx = (float)dx;
#pragma unroll
        for (int dy = -2; dy <= 2; ++dy) {
            const bool vxy = vx && ((unsigned)(y + dy) < 48u);
            const float fdy = (float)dy;
            const unsigned* pb = kw
                + ((tx + 2 + dx) * 120 + tz * 12 + (ty + 2 + dy)) * 4;

            float wsA = 0.f, wsB = 0.f;
            DO_TAP(0, vz0);
            DO_TAP(1, vz1);
            DO_TAP(2, vz2);
            DO_TAP(3, vz3);
            DO_TAP(4, vz4);
            DO_TAP(5, vz5);

            lA += wsA;  lB += wsB;
            axA = fmaf(fdx, wsA, axA);  axB = fmaf(fdx, wsB, axB);
            ayA = fmaf(fdy, wsA, ayA);  ayB = fmaf(fdy, wsB, ayB);
        }
    }
    __builtin_amdgcn_s_setprio(0);
#undef DO_TAP

    const float rA = 0.25f / lA;
    const float rB = 0.25f / lB;
    const unsigned ob = (unsigned)b * (3 * S_CHAN);
    atomicAdd(&out[ob + 0u * S_CHAN + spA],     axA * rA);
    atomicAdd(&out[ob + 0u * S_CHAN + spA + 1], axB * rB);
    atomicAdd(&out[ob + 1u * S_CHAN + spA],     ayA * rA);
    atomicAdd(&out[ob + 1u * S_CHAN + spA + 1], ayB * rB);
    atomicAdd(&out[ob + 2u * S_CHAN + spA],     azA * rA);
    atomicAdd(&out[ob + 2u * S_CHAN + spA + 1], azB * rB);
}

extern "C" void kernel_launch(void* const* d_in, const int* in_sizes, int n_in,
                              void* d_out, int out_size, void* d_ws, size_t ws_size,
                              hipStream_t stream) {
    const float* xq = (const float*)d_in[0];
    const float* xk = (const float*)d_in[1];
    float* out = (float*)d_out;
    // zero output (heads accumulate via atomicAdd); memset node is graph-capturable
    hipMemsetAsync(out, 0, (size_t)out_size * sizeof(float), stream);
    // grid: 4(head) * 2(b) * 12(xt) * 6(yt) * 3(zt) = 1728 blocks of 256 threads
    mov3d_kernel<<<1728, 256, 0, stream>>>(xq, xk, out);
}

// Round 9
// 70.086 us; speedup vs baseline: 5.0937x; 1.0448x over previous
//
#include <hip/hip_runtime.h>

// MoV3D: 3D local attention, window +-2 (125 offsets), B=2 C=32 H=W=D=48, 4 heads x 8 ch.
// Block = (b, head, 4x8x16 tile), 2 z-voxels/thread. K halo staged as fp16 channel-pairs.
// LDS line (16B) = all 8 head channels at one spatial halo point (lx,ly,lz):
//   line = lx*120 + lz2*12 + ly  (+960 for odd lz), lz2 = lz>>1   (conflict-free, r8 verified:
//   ly coeff 1 -> stride-8 lane phases hit 8 distinct bank groups; conflicts 8.3M -> 0.9M).
// Masking (this round): z-validity folded into the dot2 chain SEED (zsU in {0,-16384},
// exp2 -> exactly 0 == reference -1000 underflow, zero extra instructions); xy-validity
// applied ONCE per (dx,dy) on the aggregates (4 cndmask instead of 20 mask ops).
// 30KB LDS, launch_bounds(256,5). Scores via v_dot2_f32_f16, log2 domain -> 1-instr exp2.
// RULE-#20: no local arrays; every per-thread value is a named scalar.

#define S_PLANE 2304      // 48*48
#define S_CHAN 110592     // 48*48*48
#define TOTAL  7077888    // 2*32*S_CHAN

typedef _Float16 h2 __attribute__((ext_vector_type(2)));

__device__ __forceinline__ float dot2(h2 a, h2 b, float c) {
#if __has_builtin(__builtin_amdgcn_fdot2)
    return __builtin_amdgcn_fdot2(a, b, c, false);
#else
    return fmaf((float)a[0], (float)b[0], fmaf((float)a[1], (float)b[1], c));
#endif
}

__device__ __forceinline__ h2 bc(unsigned w) { return __builtin_bit_cast(h2, w); }
__device__ __forceinline__ unsigned pk(float a, float b) {
    return __builtin_bit_cast(unsigned, h2{(_Float16)a, (_Float16)b});
}

__global__ __launch_bounds__(256, 5) void mov3d_kernel(
    const float* __restrict__ xq, const float* __restrict__ xk,
    float* __restrict__ out)
{
    __shared__ __align__(16) unsigned kw[7680];   // 1920 lines * 16 B = 30 KB

    const int tid = threadIdx.x;
    const int tz = tid & 7;           // 8 z-threads (2 voxels each)
    const int ty = (tid >> 3) & 7;    // 8
    const int tx = tid >> 6;          // 4 (wave index)

    int blk = blockIdx.x;             // 1728 = 4(h) * [2(b) * 12(xt) * 6(yt) * 3(zt)]
    const int h = blk / 432;
    int rem = blk - h * 432;
    const int zt = rem % 3;  rem /= 3;
    const int yt = rem % 6;  rem /= 6;
    const int xt = rem % 12;
    const int b  = rem / 12;

    const int x0 = xt * 4, y0 = yt * 8, z0 = zt * 16;
    const int x = x0 + tx, y = y0 + ty, zb = z0 + 2 * tz;
    const unsigned spA = (unsigned)(x * S_PLANE + y * 48 + zb);
    const int bbase = b * (32 * S_CHAN);

    // hd^-0.5 * log2(e): scores in log2 domain
    const float QSCALE = 0.35355339059327373f * 1.4426950408889634f;

    // ---- q load & fp16 pack: qA*/qB* = {q[8p+h], q[8p+4+h]} for voxel A/B ----
    const float2 qf0 = *(const float2*)&xq[(unsigned)(bbase + (h     ) * S_CHAN) + spA];
    const float2 qf1 = *(const float2*)&xq[(unsigned)(bbase + (h +  4) * S_CHAN) + spA];
    const float2 qf2 = *(const float2*)&xq[(unsigned)(bbase + (h +  8) * S_CHAN) + spA];
    const float2 qf3 = *(const float2*)&xq[(unsigned)(bbase + (h + 12) * S_CHAN) + spA];
    const float2 qf4 = *(const float2*)&xq[(unsigned)(bbase + (h + 16) * S_CHAN) + spA];
    const float2 qf5 = *(const float2*)&xq[(unsigned)(bbase + (h + 20) * S_CHAN) + spA];
    const float2 qf6 = *(const float2*)&xq[(unsigned)(bbase + (h + 24) * S_CHAN) + spA];
    const float2 qf7 = *(const float2*)&xq[(unsigned)(bbase + (h + 28) * S_CHAN) + spA];
    const h2 qA0 = h2{(_Float16)(qf0.x * QSCALE), (_Float16)(qf1.x * QSCALE)};
    const h2 qA1 = h2{(_Float16)(qf2.x * QSCALE), (_Float16)(qf3.x * QSCALE)};
    const h2 qA2 = h2{(_Float16)(qf4.x * QSCALE), (_Float16)(qf5.x * QSCALE)};
    const h2 qA3 = h2{(_Float16)(qf6.x * QSCALE), (_Float16)(qf7.x * QSCALE)};
    const h2 qB0 = h2{(_Float16)(qf0.y * QSCALE), (_Float16)(qf1.y * QSCALE)};
    const h2 qB1 = h2{(_Float16)(qf2.y * QSCALE), (_Float16)(qf3.y * QSCALE)};
    const h2 qB2 = h2{(_Float16)(qf4.y * QSCALE), (_Float16)(qf5.y * QSCALE)};
    const h2 qB3 = h2{(_Float16)(qf6.y * QSCALE), (_Float16)(qf7.y * QSCALE)};

    // ---- stage K halo: thread u covers lz pair (2*lz2, 2*lz2+1) at (lx,ly) ----
    const int sBase = bbase + h * S_CHAN;
#pragma unroll
    for (int i = 0; i < 4; ++i) {
        const int u = i * 256 + tid;
        if (u < 960) {
            const int lx  = u / 120;
            const int r   = u - lx * 120;
            const int ly  = r / 10;
            const int lz2 = r - ly * 10;
            const int m = lx * 120 + lz2 * 12 + ly;   // even-parity line
            const int f = sBase + (x0 - 2 + lx) * S_PLANE + (y0 - 2 + ly) * 48
                        + (z0 - 2 + 2 * lz2);
            const int a0 = min(max(f,                0), TOTAL - 2);
            const int a1 = min(max(f +  8 * S_CHAN,  0), TOTAL - 2);
            const int a2 = min(max(f + 16 * S_CHAN,  0), TOTAL - 2);
            const int a3 = min(max(f + 24 * S_CHAN,  0), TOTAL - 2);
            const int c0 = min(max(f +  4 * S_CHAN,  0), TOTAL - 2);
            const int c1 = min(max(f + 12 * S_CHAN,  0), TOTAL - 2);
            const int c2 = min(max(f + 20 * S_CHAN,  0), TOTAL - 2);
            const int c3 = min(max(f + 28 * S_CHAN,  0), TOTAL - 2);
            const float2 vA0 = *(const float2*)&xk[a0];
            const float2 vA1 = *(const float2*)&xk[a1];
            const float2 vA2 = *(const float2*)&xk[a2];
            const float2 vA3 = *(const float2*)&xk[a3];
            const float2 vB0 = *(const float2*)&xk[c0];
            const float2 vB1 = *(const float2*)&xk[c1];
            const float2 vB2 = *(const float2*)&xk[c2];
            const float2 vB3 = *(const float2*)&xk[c3];
            const uint4 W0 = {pk(vA0.x, vB0.x), pk(vA1.x, vB1.x),
                              pk(vA2.x, vB2.x), pk(vA3.x, vB3.x)};
            const uint4 W1 = {pk(vA0.y, vB0.y), pk(vA1.y, vB1.y),
                              pk(vA2.y, vB2.y), pk(vA3.y, vB3.y)};
            *(uint4*)&kw[m * 4] = W0;               // lz even
            *(uint4*)&kw[(m + 960) * 4] = W1;       // lz odd
        }
    }
    __syncthreads();   // single barrier

    // z-validity seeds: slot U covers abs z = zb-2+U; invalid -> exp2(dot-16384) == 0
    const float NEG = -16384.f;
    const float zs0 = ((unsigned)(zb - 2) < 48u) ? 0.f : NEG;
    const float zs1 = ((unsigned)(zb - 1) < 48u) ? 0.f : NEG;
    const float zs2 = 0.f;                           // zb in [0,48)
    const float zs3 = ((unsigned)(zb + 1) < 48u) ? 0.f : NEG;
    const float zs4 = ((unsigned)(zb + 2) < 48u) ? 0.f : NEG;
    const float zs5 = ((unsigned)(zb + 3) < 48u) ? 0.f : NEG;

    float lA = 0.f, axA = 0.f, ayA = 0.f, azA = 0.f;
    float lB = 0.f, axB = 0.f, ayB = 0.f, azB = 0.f;

#define SCORE(Q0, Q1, Q2, Q3, T, SEED) \
    dot2(Q0, bc((T).x), dot2(Q1, bc((T).y), dot2(Q2, bc((T).z), dot2(Q3, bc((T).w), (SEED)))))

    __builtin_amdgcn_s_setprio(1);
#pragma unroll
    for (int dx = -2; dx <= 2; ++dx) {
        const bool vx = (unsigned)(x + dx) < 48u;
        const float fdx = (float)dx;
#pragma unroll
        for (int dy = -2; dy <= 2; ++dy) {
            const bool vxy = vx && ((unsigned)(y + dy) < 48u);
            const float fdy = (float)dy;
            const unsigned* pb = kw
                + ((tx + 2 + dx) * 120 + tz * 12 + (ty + 2 + dy)) * 4;

            // window slots U=0..5: word offset (U>>1)*48 + (U&1)*3840
            const uint4 T0 = *(const uint4*)(pb);
            const uint4 T1 = *(const uint4*)(pb + 3840);
            const uint4 T2 = *(const uint4*)(pb + 48);
            const uint4 T3 = *(const uint4*)(pb + 48 + 3840);
            const uint4 T4 = *(const uint4*)(pb + 96);
            const uint4 T5 = *(const uint4*)(pb + 96 + 3840);

            // voxel A taps slots 0..4, voxel B taps slots 1..5 (z-seed folded in)
            const float eA0 = exp2f(SCORE(qA0, qA1, qA2, qA3, T0, zs0));
            const float eA1 = exp2f(SCORE(qA0, qA1, qA2, qA3, T1, zs1));
            const float eA2 = exp2f(SCORE(qA0, qA1, qA2, qA3, T2, zs2));
            const float eA3 = exp2f(SCORE(qA0, qA1, qA2, qA3, T3, zs3));
            const float eA4 = exp2f(SCORE(qA0, qA1, qA2, qA3, T4, zs4));
            const float eB0 = exp2f(SCORE(qB0, qB1, qB2, qB3, T1, zs1));
            const float eB1 = exp2f(SCORE(qB0, qB1, qB2, qB3, T2, zs2));
            const float eB2 = exp2f(SCORE(qB0, qB1, qB2, qB3, T3, zs3));
            const float eB3 = exp2f(SCORE(qB0, qB1, qB2, qB3, T4, zs4));
            const float eB4 = exp2f(SCORE(qB0, qB1, qB2, qB3, T5, zs5));

            float wsA  = ((eA0 + eA1) + (eA2 + eA3)) + eA4;
            float wsB  = ((eB0 + eB1) + (eB2 + eB3)) + eB4;
            float azPA = fmaf(2.f, eA4 - eA0, eA3 - eA1);
            float azPB = fmaf(2.f, eB4 - eB0, eB3 - eB1);

            // xy-mask applied once on the aggregates (shared by all 5 z-taps)
            wsA  = vxy ? wsA  : 0.f;
            wsB  = vxy ? wsB  : 0.f;
            azPA = vxy ? azPA : 0.f;
            azPB = vxy ? azPB : 0.f;

            lA += wsA;  lB += wsB;
            axA = fmaf(fdx, wsA, axA);  axB = fmaf(fdx, wsB, axB);
            ayA = fmaf(fdy, wsA, ayA);  ayB = fmaf(fdy, wsB, ayB);
            azA += azPA;  azB += azPB;
        }
    }
    __builtin_amdgcn_s_setprio(0);
#undef SCORE

    const float rA = 0.25f / lA;
    const float rB = 0.25f / lB;
    const unsigned ob = (unsigned)b * (3 * S_CHAN);
    atomicAdd(&out[ob + 0u * S_CHAN + spA],     axA * rA);
    atomicAdd(&out[ob + 0u * S_CHAN + spA + 1], axB * rB);
    atomicAdd(&out[ob + 1u * S_CHAN + spA],     ayA * rA);
    atomicAdd(&out[ob + 1u * S_CHAN + spA + 1], ayB * rB);
    atomicAdd(&out[ob + 2u * S_CHAN + spA],     azA * rA);
    atomicAdd(&out[ob + 2u * S_CHAN + spA + 1], azB * rB);
}

extern "C" void kernel_launch(void* const* d_in, const int* in_sizes, int n_in,
                              void* d_out, int out_size, void* d_ws, size_t ws_size,
                              hipStream_t stream) {
    const float* xq = (const float*)d_in[0];
    const float* xk = (const float*)d_in[1];
    float* out = (float*)d_out;
    // zero output (heads accumulate via atomicAdd); memset node is graph-capturable
    hipMemsetAsync(out, 0, (size_t)out_size * sizeof(float), stream);
    // grid: 4(head) * 2(b) * 12(xt) * 6(yt) * 3(zt) = 1728 blocks of 256 threads
    mov3d_kernel<<<1728, 256, 0, stream>>>(xq, xk, out);
}